// Round 2
// baseline (420.827 us; speedup 1.0000x reference)
//
#include <hip/hip_runtime.h>
#include <hip/hip_bf16.h>
#include <hip/hip_fp16.h>
#include <math.h>

#define T_TOK 2048
#define HDIM  1024
#define NEXP  16
#define IDIM  768
#define BM    32
#define MAXROWS 4608   // 2*T + 16*31 = 4592 padded rows, rounded up

using f16   = _Float16;
using f16x4 = __attribute__((ext_vector_type(4))) _Float16;
using f16x8 = __attribute__((ext_vector_type(8))) _Float16;
using f32x4 = __attribute__((ext_vector_type(4))) float;

// ---------------- router: fp32 logits, top-2, renormalized gates ----------------
__global__ __launch_bounds__(256) void router_kernel(
    const float* __restrict__ x, const float* __restrict__ gw,
    int* __restrict__ tok_e, float* __restrict__ tok_w, int* __restrict__ cnt)
{
    int wave = threadIdx.x >> 6;
    int lane = threadIdx.x & 63;
    int t = blockIdx.x * 4 + wave;
    if (t >= T_TOK) return;

    const float* xrow = x + (size_t)t * HDIM;
    float xv[16];
#pragma unroll
    for (int j = 0; j < 16; ++j) xv[j] = xrow[lane + 64 * j];

    float logits[NEXP];
#pragma unroll
    for (int e = 0; e < NEXP; ++e) {
        const float* gr = gw + (size_t)e * HDIM;
        float s = 0.f;
#pragma unroll
        for (int j = 0; j < 16; ++j) s += xv[j] * gr[lane + 64 * j];
#pragma unroll
        for (int o = 32; o > 0; o >>= 1) s += __shfl_xor(s, o, 64);
        logits[e] = s;
    }

    // top-2 (strict > keeps lowest index on ties, matching jax top_k)
    int i1 = 0; float m1 = logits[0];
#pragma unroll
    for (int e = 1; e < NEXP; ++e) if (logits[e] > m1) { m1 = logits[e]; i1 = e; }
    int i2 = -1; float m2 = -3.0e38f;
#pragma unroll
    for (int e = 0; e < NEXP; ++e) if (e != i1 && logits[e] > m2) { m2 = logits[e]; i2 = e; }

    // renormalized top-2 softmax weights: denominator cancels
    float w1 = 1.f / (1.f + expf(m2 - m1));
    float w2 = 1.f - w1;

    if (lane == 0) {
        tok_e[t * 2 + 0] = i1; tok_e[t * 2 + 1] = i2;
        tok_w[t * 2 + 0] = w1; tok_w[t * 2 + 1] = w2;
        atomicAdd(&cnt[i1], 1);
        atomicAdd(&cnt[i2], 1);
    }
}

// ---------------- prefix: padded (to BM) expert bases ----------------
__global__ void prefix_kernel(const int* __restrict__ cnt, int* __restrict__ base,
                              int* __restrict__ total)
{
    if (threadIdx.x == 0) {
        int b = 0;
        for (int e = 0; e < NEXP; ++e) {
            base[e] = b;
            b += (cnt[e] + BM - 1) & ~(BM - 1);
        }
        base[NEXP] = b;
        *total = b;
    }
}

// ---------------- scatter: compact expert-major row list ----------------
__global__ __launch_bounds__(256) void scatter_kernel(
    const int* __restrict__ tok_e, const float* __restrict__ tok_w,
    const int* __restrict__ base, int* __restrict__ cnt2,
    int* __restrict__ rowslot, float* __restrict__ rowgate)
{
    int t = blockIdx.x * 256 + threadIdx.x;
    if (t >= T_TOK) return;
#pragma unroll
    for (int k = 0; k < 2; ++k) {
        int e = tok_e[t * 2 + k];
        int pos = atomicAdd(&cnt2[e], 1);
        int row = base[e] + pos;
        rowslot[row] = t * 2 + k;
        rowgate[row] = tok_w[t * 2 + k];
    }
}

// ---------------- GEMM1: h = x_gathered @ w13_e^T, fused SwiGLU -> act (fp16) ----------------
// tile: 32 rows x 128 cols of h (= 64 gate cols + the matching 64 up cols)
__global__ __launch_bounds__(256) void gemm1_kernel(
    const float* __restrict__ x, const float* __restrict__ w13,
    const int* __restrict__ rowslot, const int* __restrict__ base,
    const int* __restrict__ cnt, const int* __restrict__ total,
    f16* __restrict__ act)
{
    int row0 = blockIdx.x * BM;
    if (row0 >= *total) return;
    int nt = blockIdx.y;  // 0..11, 64 act cols each

    int e = 0;
#pragma unroll
    for (int i = 1; i < NEXP; ++i) if (base[i] <= row0) e = i;
    int basee = base[e], cnte = cnt[e];

    __shared__ f16  a_sm[32 * 40];
    __shared__ f16  b_sm[128 * 40];
    __shared__ float h_sm[32 * 132];

    int tid = threadIdx.x;

    // A staging: thread -> (row ar, 4 k-cols at ac)
    int ar = tid >> 3, ac = (tid & 7) * 4;
    bool avalid = (row0 + ar - basee) < cnte;
    const float* aptr = x;  // dummy
    if (avalid) {
        int tok = rowslot[row0 + ar] >> 1;
        aptr = x + (size_t)tok * HDIM + ac;
    }

    // B staging: thread -> (row br of 128, 16 k-cols at bc)
    int br = tid >> 1, bc = (tid & 1) * 16;
    int wrow = (br < 64) ? (nt * 64 + br) : (IDIM + nt * 64 + (br - 64));
    const float* bptr = w13 + (size_t)e * 2 * IDIM * HDIM + (size_t)wrow * HDIM + bc;

    int wv = tid >> 6, lane = tid & 63, l16 = lane & 15, lk = lane >> 4;
    f32x4 acc[2][2] = {};

    for (int k0 = 0; k0 < HDIM; k0 += 32) {
        __syncthreads();
        // stage A (fp32 -> fp16)
        float4 av = avalid ? *(const float4*)(aptr + k0) : float4{0.f, 0.f, 0.f, 0.f};
        f16x4 a4; a4[0] = (f16)av.x; a4[1] = (f16)av.y; a4[2] = (f16)av.z; a4[3] = (f16)av.w;
        *(f16x4*)&a_sm[ar * 40 + ac] = a4;
        // stage B (fp32 -> fp16), 16 elements
#pragma unroll
        for (int i = 0; i < 4; ++i) {
            float4 bv = *(const float4*)(bptr + k0 + i * 4);
            f16x4 b4; b4[0] = (f16)bv.x; b4[1] = (f16)bv.y; b4[2] = (f16)bv.z; b4[3] = (f16)bv.w;
            *(f16x4*)&b_sm[br * 40 + bc + i * 4] = b4;
        }
        __syncthreads();

        f16x8 af0 = *(const f16x8*)&a_sm[(l16) * 40 + lk * 8];
        f16x8 af1 = *(const f16x8*)&a_sm[(16 + l16) * 40 + lk * 8];
        f16x8 bf0 = *(const f16x8*)&b_sm[(wv * 32 + l16) * 40 + lk * 8];
        f16x8 bf1 = *(const f16x8*)&b_sm[(wv * 32 + 16 + l16) * 40 + lk * 8];
        acc[0][0] = __builtin_amdgcn_mfma_f32_16x16x32_f16(af0, bf0, acc[0][0], 0, 0, 0);
        acc[0][1] = __builtin_amdgcn_mfma_f32_16x16x32_f16(af0, bf1, acc[0][1], 0, 0, 0);
        acc[1][0] = __builtin_amdgcn_mfma_f32_16x16x32_f16(af1, bf0, acc[1][0], 0, 0, 0);
        acc[1][1] = __builtin_amdgcn_mfma_f32_16x16x32_f16(af1, bf1, acc[1][1], 0, 0, 0);
    }

    __syncthreads();
    // D mapping: n = lane&15, m = (lane>>4)*4 + reg  [m89/m91-verified]
#pragma unroll
    for (int mh = 0; mh < 2; ++mh)
#pragma unroll
        for (int nh = 0; nh < 2; ++nh)
#pragma unroll
            for (int j = 0; j < 4; ++j)
                h_sm[(mh * 16 + lk * 4 + j) * 132 + wv * 32 + nh * 16 + l16] = acc[mh][nh][j];
    __syncthreads();

    // SwiGLU epilogue: act = silu(h_gate) * h_up, 32x64 outputs
    int rr = tid >> 3, cc = (tid & 7) * 8;
    f16x8 o;
#pragma unroll
    for (int i = 0; i < 8; ++i) {
        float hg = h_sm[rr * 132 + cc + i];
        float hu = h_sm[rr * 132 + 64 + cc + i];
        float s = hg / (1.f + expf(-hg));
        o[i] = (f16)(s * hu);
    }
    *(f16x8*)&act[(size_t)(row0 + rr) * IDIM + nt * 64 + cc] = o;
}

// ---------------- GEMM2: z = act @ w2_e^T, scaled by gate, atomicAdd into out ----------------
__global__ __launch_bounds__(256) void gemm2_kernel(
    const f16* __restrict__ act, const float* __restrict__ w2,
    const int* __restrict__ rowslot, const float* __restrict__ rowgate,
    const int* __restrict__ base, const int* __restrict__ cnt, const int* __restrict__ total,
    float* __restrict__ out)
{
    int row0 = blockIdx.x * BM;
    if (row0 >= *total) return;
    int nt = blockIdx.y;  // 0..7, 128 H-cols each

    int e = 0;
#pragma unroll
    for (int i = 1; i < NEXP; ++i) if (base[i] <= row0) e = i;
    int basee = base[e], cnte = cnt[e];

    __shared__ f16 a_sm[32 * 40];
    __shared__ f16 b_sm[128 * 40];

    int tid = threadIdx.x;
    int ar = tid >> 3, ac = (tid & 7) * 4;
    const f16* aptr = act + (size_t)(row0 + ar) * IDIM + ac;
    int br = tid >> 1, bc = (tid & 1) * 16;
    const float* bptr = w2 + (size_t)e * HDIM * IDIM + (size_t)(nt * 128 + br) * IDIM + bc;

    int wv = tid >> 6, lane = tid & 63, l16 = lane & 15, lk = lane >> 4;
    f32x4 acc[2][2] = {};

    for (int k0 = 0; k0 < IDIM; k0 += 32) {
        __syncthreads();
        *(f16x4*)&a_sm[ar * 40 + ac] = *(const f16x4*)(aptr + k0);
#pragma unroll
        for (int i = 0; i < 4; ++i) {
            float4 bv = *(const float4*)(bptr + k0 + i * 4);
            f16x4 b4; b4[0] = (f16)bv.x; b4[1] = (f16)bv.y; b4[2] = (f16)bv.z; b4[3] = (f16)bv.w;
            *(f16x4*)&b_sm[br * 40 + bc + i * 4] = b4;
        }
        __syncthreads();

        f16x8 af0 = *(const f16x8*)&a_sm[(l16) * 40 + lk * 8];
        f16x8 af1 = *(const f16x8*)&a_sm[(16 + l16) * 40 + lk * 8];
        f16x8 bf0 = *(const f16x8*)&b_sm[(wv * 32 + l16) * 40 + lk * 8];
        f16x8 bf1 = *(const f16x8*)&b_sm[(wv * 32 + 16 + l16) * 40 + lk * 8];
        acc[0][0] = __builtin_amdgcn_mfma_f32_16x16x32_f16(af0, bf0, acc[0][0], 0, 0, 0);
        acc[0][1] = __builtin_amdgcn_mfma_f32_16x16x32_f16(af0, bf1, acc[0][1], 0, 0, 0);
        acc[1][0] = __builtin_amdgcn_mfma_f32_16x16x32_f16(af1, bf0, acc[1][0], 0, 0, 0);
        acc[1][1] = __builtin_amdgcn_mfma_f32_16x16x32_f16(af1, bf1, acc[1][1], 0, 0, 0);
    }

    int colbase = nt * 128 + wv * 32;
#pragma unroll
    for (int mh = 0; mh < 2; ++mh) {
#pragma unroll
        for (int j = 0; j < 4; ++j) {
            int r = mh * 16 + lk * 4 + j;
            int row = row0 + r;
            if ((row - basee) < cnte) {
                int s = rowslot[row];
                float g = rowgate[row];
                float* orow = out + (size_t)(s >> 1) * HDIM + colbase;
                atomicAdd(&orow[l16], g * acc[mh][0][j]);
                atomicAdd(&orow[16 + l16], g * acc[mh][1][j]);
            }
        }
    }
}

extern "C" void kernel_launch(void* const* d_in, const int* in_sizes, int n_in,
                              void* d_out, int out_size, void* d_ws, size_t ws_size,
                              hipStream_t stream) {
    const float* x   = (const float*)d_in[0];
    const float* gw  = (const float*)d_in[1];
    const float* w13 = (const float*)d_in[2];
    const float* w2  = (const float*)d_in[3];
    float* out = (float*)d_out;

    char* ws = (char*)d_ws;
    size_t off = 0;
    f16* act       = (f16*)(ws + off);   off += (size_t)MAXROWS * IDIM * 2;
    int* rowslot   = (int*)(ws + off);   off += (size_t)MAXROWS * 4;
    float* rowgate = (float*)(ws + off); off += (size_t)MAXROWS * 4;
    int* tok_e     = (int*)(ws + off);   off += (size_t)T_TOK * 2 * 4;
    float* tok_w   = (float*)(ws + off); off += (size_t)T_TOK * 2 * 4;
    int* cnt       = (int*)(ws + off);   off += 64;
    int* cnt2      = (int*)(ws + off);   off += 64;
    int* base      = (int*)(ws + off);   off += 128;
    int* total     = (int*)(ws + off);   off += 64;

    hipMemsetAsync(cnt, 0, 128, stream);  // cnt + cnt2 (contiguous)
    hipMemsetAsync(out, 0, (size_t)T_TOK * HDIM * 4, stream);

    router_kernel<<<T_TOK / 4, 256, 0, stream>>>(x, gw, tok_e, tok_w, cnt);
    prefix_kernel<<<1, 64, 0, stream>>>(cnt, base, total);
    scatter_kernel<<<T_TOK / 256, 256, 0, stream>>>(tok_e, tok_w, base, cnt2, rowslot, rowgate);

    dim3 g1(MAXROWS / BM, (2 * IDIM) / 128);  // 144 x 12
    gemm1_kernel<<<g1, 256, 0, stream>>>(x, w13, rowslot, base, cnt, total, act);

    dim3 g2(MAXROWS / BM, HDIM / 128);        // 144 x 8
    gemm2_kernel<<<g2, 256, 0, stream>>>(act, w2, rowslot, rowgate, base, cnt, total, out);
}

// Round 4
// 353.314 us; speedup vs baseline: 1.1911x; 1.1911x over previous
//
#include <hip/hip_runtime.h>
#include <hip/hip_bf16.h>
#include <hip/hip_fp16.h>
#include <math.h>

#define T_TOK 2048
#define HDIM  1024
#define NEXP  16
#define IDIM  768
#define BM    128
#define MAXROWS 6144   // 4096 real slots + 16*127 max pad, rounded to 128

using f16   = _Float16;
using f16x4 = __attribute__((ext_vector_type(4))) _Float16;
using f16x8 = __attribute__((ext_vector_type(8))) _Float16;
using f32x4 = __attribute__((ext_vector_type(4))) float;

__device__ __forceinline__ f16x8 cvt2(float4 a, float4 b) {
    f16x8 r;
    r[0] = (f16)a.x; r[1] = (f16)a.y; r[2] = (f16)a.z; r[3] = (f16)a.w;
    r[4] = (f16)b.x; r[5] = (f16)b.y; r[6] = (f16)b.z; r[7] = (f16)b.w;
    return r;
}

// ---------------- router: fp32 logits, top-2, renormalized gates ----------------
__global__ __launch_bounds__(256) void router_kernel(
    const float* __restrict__ x, const float* __restrict__ gw,
    int* __restrict__ tok_e, float* __restrict__ tok_w, int* __restrict__ cnt)
{
    int wave = threadIdx.x >> 6;
    int lane = threadIdx.x & 63;
    int t = blockIdx.x * 4 + wave;
    if (t >= T_TOK) return;

    const float* xrow = x + (size_t)t * HDIM;
    float xv[16];
#pragma unroll
    for (int j = 0; j < 16; ++j) xv[j] = xrow[lane + 64 * j];

    float logits[NEXP];
#pragma unroll
    for (int e = 0; e < NEXP; ++e) {
        const float* gr = gw + (size_t)e * HDIM;
        float s = 0.f;
#pragma unroll
        for (int j = 0; j < 16; ++j) s += xv[j] * gr[lane + 64 * j];
#pragma unroll
        for (int o = 32; o > 0; o >>= 1) s += __shfl_xor(s, o, 64);
        logits[e] = s;
    }

    int i1 = 0; float m1 = logits[0];
#pragma unroll
    for (int e = 1; e < NEXP; ++e) if (logits[e] > m1) { m1 = logits[e]; i1 = e; }
    int i2 = -1; float m2 = -3.0e38f;
#pragma unroll
    for (int e = 0; e < NEXP; ++e) if (e != i1 && logits[e] > m2) { m2 = logits[e]; i2 = e; }

    float w1 = 1.f / (1.f + expf(m2 - m1));
    float w2 = 1.f - w1;

    if (lane == 0) {
        tok_e[t * 2 + 0] = i1; tok_e[t * 2 + 1] = i2;
        tok_w[t * 2 + 0] = w1; tok_w[t * 2 + 1] = w2;
        atomicAdd(&cnt[i1], 1);
        atomicAdd(&cnt[i2], 1);
    }
}

// ---------------- prefix: padded (to BM=128) expert bases ----------------
__global__ void prefix_kernel(const int* __restrict__ cnt, int* __restrict__ base,
                              int* __restrict__ total)
{
    if (threadIdx.x == 0) {
        int b = 0;
        for (int e = 0; e < NEXP; ++e) {
            base[e] = b;
            b += (cnt[e] + BM - 1) & ~(BM - 1);
        }
        base[NEXP] = b;
        *total = b;
    }
}

// ---------------- scatter: compact expert-major row list ----------------
__global__ __launch_bounds__(256) void scatter_kernel(
    const int* __restrict__ tok_e, const float* __restrict__ tok_w,
    const int* __restrict__ base, int* __restrict__ cnt2,
    int* __restrict__ rowslot, float* __restrict__ rowgate)
{
    int t = blockIdx.x * 256 + threadIdx.x;
    if (t >= T_TOK) return;
#pragma unroll
    for (int k = 0; k < 2; ++k) {
        int e = tok_e[t * 2 + k];
        int pos = atomicAdd(&cnt2[e], 1);
        int row = base[e] + pos;
        rowslot[row] = t * 2 + k;
        rowgate[row] = tok_w[t * 2 + k];
    }
}

// ---------------- GEMM1: 128x128 tile, h = x @ w13_e^T, in-register SwiGLU -> act ----------------
// grid (48, 12); 4 waves, each computes 32 rows x 128 cols (gate cols n<4, up cols n>=4)
__global__ __launch_bounds__(256) void gemm1_kernel(
    const float* __restrict__ x, const float* __restrict__ w13,
    const int* __restrict__ rowslot, const int* __restrict__ base,
    const int* __restrict__ cnt, const int* __restrict__ total,
    f16* __restrict__ act)
{
    int row0 = blockIdx.x * BM;
    if (row0 >= *total) return;
    int nt = blockIdx.y;  // 0..11, 64 act cols each

    int e = 0;
#pragma unroll
    for (int i = 1; i < NEXP; ++i) if (base[i] <= row0) e = i;
    int basee = base[e], cnte = cnt[e];

    __shared__ f16 a_sm[128 * 40];   // 128 rows x 32 k, stride 40
    __shared__ f16 b_sm[128 * 40];

    int tid = threadIdx.x;
    int srow = tid >> 1;            // 0..127
    int scol = (tid & 1) * 16;      // 0 or 16

    // A source (gathered token row, fp32), zero for pad rows
    bool avalid = (unsigned)(row0 + srow - basee) < (unsigned)cnte;
    const float* aptr = x;
    if (avalid) {
        int tok = rowslot[row0 + srow] >> 1;
        aptr = x + (size_t)tok * HDIM + scol;
    }

    // B source: h-col srow of this nt tile (gate half then up half)
    int wrow = (srow < 64) ? (nt * 64 + srow) : (IDIM + nt * 64 + (srow - 64));
    const float* bptr = w13 + (size_t)e * 2 * IDIM * HDIM + (size_t)wrow * HDIM + scol;

    int wv = tid >> 6, lane = tid & 63, l16 = lane & 15, lk = lane >> 4;
    f32x4 acc[2][8] = {};

    for (int k0 = 0; k0 < HDIM; k0 += 32) {
        __syncthreads();
        {
            float4 a0{0,0,0,0}, a1{0,0,0,0}, a2{0,0,0,0}, a3{0,0,0,0};
            if (avalid) {
                a0 = *(const float4*)(aptr + k0);
                a1 = *(const float4*)(aptr + k0 + 4);
                a2 = *(const float4*)(aptr + k0 + 8);
                a3 = *(const float4*)(aptr + k0 + 12);
            }
            float4 b0 = *(const float4*)(bptr + k0);
            float4 b1 = *(const float4*)(bptr + k0 + 4);
            float4 b2 = *(const float4*)(bptr + k0 + 8);
            float4 b3 = *(const float4*)(bptr + k0 + 12);
            *(f16x8*)&a_sm[srow * 40 + scol]     = cvt2(a0, a1);
            *(f16x8*)&a_sm[srow * 40 + scol + 8] = cvt2(a2, a3);
            *(f16x8*)&b_sm[srow * 40 + scol]     = cvt2(b0, b1);
            *(f16x8*)&b_sm[srow * 40 + scol + 8] = cvt2(b2, b3);
        }
        __syncthreads();

        f16x8 af[2], bf[8];
#pragma unroll
        for (int m = 0; m < 2; ++m)
            af[m] = *(const f16x8*)&a_sm[(wv * 32 + m * 16 + l16) * 40 + lk * 8];
#pragma unroll
        for (int n = 0; n < 8; ++n)
            bf[n] = *(const f16x8*)&b_sm[(n * 16 + l16) * 40 + lk * 8];
#pragma unroll
        for (int m = 0; m < 2; ++m)
#pragma unroll
            for (int n = 0; n < 8; ++n)
                acc[m][n] = __builtin_amdgcn_mfma_f32_16x16x32_f16(af[m], bf[n], acc[m][n], 0, 0, 0);
    }

    // in-register SwiGLU epilogue: gate frag n pairs with up frag n+4, same lane/reg
#pragma unroll
    for (int m = 0; m < 2; ++m)
#pragma unroll
        for (int n = 0; n < 4; ++n)
#pragma unroll
            for (int j = 0; j < 4; ++j) {
                float hg = acc[m][n][j];
                float hu = acc[m][n + 4][j];
                float s = hg / (1.f + expf(-hg));
                int row = row0 + wv * 32 + m * 16 + lk * 4 + j;
                act[(size_t)row * IDIM + nt * 64 + n * 16 + l16] = (f16)(s * hu);
            }
}

// ---------------- GEMM2: 128x128 tile, z = act @ w2_e^T, gate-scaled atomicAdd ----------------
// grid (48, 8); 4 waves, each 32 rows x 128 cols
__global__ __launch_bounds__(256) void gemm2_kernel(
    const f16* __restrict__ act, const float* __restrict__ w2,
    const int* __restrict__ rowslot, const float* __restrict__ rowgate,
    const int* __restrict__ base, const int* __restrict__ cnt, const int* __restrict__ total,
    float* __restrict__ out)
{
    int row0 = blockIdx.x * BM;
    if (row0 >= *total) return;
    int nt = blockIdx.y;  // 0..7, 128 H-cols each

    int e = 0;
#pragma unroll
    for (int i = 1; i < NEXP; ++i) if (base[i] <= row0) e = i;
    int basee = base[e], cnte = cnt[e];

    __shared__ f16 a_sm[128 * 40];
    __shared__ f16 b_sm[128 * 40];

    int tid = threadIdx.x;
    int srow = tid >> 1;
    int scol = (tid & 1) * 16;

    const f16*   aptr = act + (size_t)(row0 + srow) * IDIM + scol;
    const float* bptr = w2 + (size_t)e * HDIM * IDIM + (size_t)(nt * 128 + srow) * IDIM + scol;

    int wv = tid >> 6, lane = tid & 63, l16 = lane & 15, lk = lane >> 4;
    f32x4 acc[2][8] = {};

    for (int k0 = 0; k0 < IDIM; k0 += 32) {
        __syncthreads();
        {
            f16x8 alo = *(const f16x8*)(aptr + k0);
            f16x8 ahi = *(const f16x8*)(aptr + k0 + 8);
            float4 b0 = *(const float4*)(bptr + k0);
            float4 b1 = *(const float4*)(bptr + k0 + 4);
            float4 b2 = *(const float4*)(bptr + k0 + 8);
            float4 b3 = *(const float4*)(bptr + k0 + 12);
            *(f16x8*)&a_sm[srow * 40 + scol]     = alo;
            *(f16x8*)&a_sm[srow * 40 + scol + 8] = ahi;
            *(f16x8*)&b_sm[srow * 40 + scol]     = cvt2(b0, b1);
            *(f16x8*)&b_sm[srow * 40 + scol + 8] = cvt2(b2, b3);
        }
        __syncthreads();

        f16x8 af[2], bf[8];
#pragma unroll
        for (int m = 0; m < 2; ++m)
            af[m] = *(const f16x8*)&a_sm[(wv * 32 + m * 16 + l16) * 40 + lk * 8];
#pragma unroll
        for (int n = 0; n < 8; ++n)
            bf[n] = *(const f16x8*)&b_sm[(n * 16 + l16) * 40 + lk * 8];
#pragma unroll
        for (int m = 0; m < 2; ++m)
#pragma unroll
            for (int n = 0; n < 8; ++n)
                acc[m][n] = __builtin_amdgcn_mfma_f32_16x16x32_f16(af[m], bf[n], acc[m][n], 0, 0, 0);
    }

#pragma unroll
    for (int m = 0; m < 2; ++m)
#pragma unroll
        for (int j = 0; j < 4; ++j) {
            int row = row0 + wv * 32 + m * 16 + lk * 4 + j;
            if ((unsigned)(row - basee) < (unsigned)cnte) {
                int s = rowslot[row];
                float g = rowgate[row];
                float* orow = out + (size_t)(s >> 1) * HDIM + nt * 128;
#pragma unroll
                for (int n = 0; n < 8; ++n)
                    atomicAdd(&orow[n * 16 + l16], g * acc[m][n][j]);
            }
        }
}

extern "C" void kernel_launch(void* const* d_in, const int* in_sizes, int n_in,
                              void* d_out, int out_size, void* d_ws, size_t ws_size,
                              hipStream_t stream) {
    const float* x   = (const float*)d_in[0];
    const float* gw  = (const float*)d_in[1];
    const float* w13 = (const float*)d_in[2];
    const float* w2  = (const float*)d_in[3];
    float* out = (float*)d_out;

    char* ws = (char*)d_ws;
    size_t off = 0;
    f16* act       = (f16*)(ws + off);   off += (size_t)MAXROWS * IDIM * 2;
    int* rowslot   = (int*)(ws + off);   off += (size_t)MAXROWS * 4;
    float* rowgate = (float*)(ws + off); off += (size_t)MAXROWS * 4;
    int* tok_e     = (int*)(ws + off);   off += (size_t)T_TOK * 2 * 4;
    float* tok_w   = (float*)(ws + off); off += (size_t)T_TOK * 2 * 4;
    int* cnt       = (int*)(ws + off);   off += 64;
    int* cnt2      = (int*)(ws + off);   off += 64;
    int* base      = (int*)(ws + off);   off += 128;
    int* total     = (int*)(ws + off);   off += 64;

    hipMemsetAsync(cnt, 0, 128, stream);  // cnt + cnt2 (contiguous)
    hipMemsetAsync(out, 0, (size_t)T_TOK * HDIM * 4, stream);

    router_kernel<<<T_TOK / 4, 256, 0, stream>>>(x, gw, tok_e, tok_w, cnt);
    prefix_kernel<<<1, 64, 0, stream>>>(cnt, base, total);
    scatter_kernel<<<T_TOK / 256, 256, 0, stream>>>(tok_e, tok_w, base, cnt2, rowslot, rowgate);

    dim3 g1(MAXROWS / BM, (2 * IDIM) / 128);  // 48 x 12
    gemm1_kernel<<<g1, 256, 0, stream>>>(x, w13, rowslot, base, cnt, total, act);

    dim3 g2(MAXROWS / BM, HDIM / 128);        // 48 x 8
    gemm2_kernel<<<g2, 256, 0, stream>>>(act, w2, rowslot, rowgate, base, cnt, total, out);
}